// Round 5
// baseline (1356.132 us; speedup 1.0000x reference)
//
#include <hip/hip_runtime.h>
#include <hip/hip_bf16.h>
#include <stdint.h>

// ---------------------------------------------------------------------------
// BoardEmbeddingWithTopology: embed GEMM -> QKV GEMM -> per-head attention
// with learned 64x64 relative bias -> O-proj GEMM + residual -> LayerNorm.
// R6: revert GEMMs to the R1-proven 256x256 BK=64 8-wave 8-phase core
// (438 us, 0 bank conflicts; the 128^2 2-blocks/CU experiment REGRESSED:
// MfmaUtil 34%, 4-way read conflicts from a wrong swizzle function).
// Tweak: ph4 vmcnt(4) moved after the MFMA cluster (overlap drain w/ MFMA).
// New: LayerNorm = 1 wave/row, 4096 blocks (was 65536 tiny blocks);
// 4 weight transposes merged into one kernel.
// ---------------------------------------------------------------------------

typedef float  floatx4 __attribute__((ext_vector_type(4)));
typedef short  bf16x8  __attribute__((ext_vector_type(8)));
typedef short  bf16x4  __attribute__((ext_vector_type(4)));

__device__ __forceinline__ short f2bf(float f) {
  __hip_bfloat16 h = __float2bfloat16(f);
  return *reinterpret_cast<short*>(&h);
}
__device__ __forceinline__ float bf2f(short s) {
  union { float f; uint32_t u; } c;
  c.u = ((uint32_t)(uint16_t)s) << 16;
  return c.f;
}
__device__ __forceinline__ floatx4 mfma16(bf16x8 a, bf16x8 b, floatx4 c) {
  return __builtin_amdgcn_mfma_f32_16x16x32_bf16(a, b, c, 0, 0, 0);
}

// async global->LDS, 16B per lane; lds dst must be wave-uniform base.
#define ASYNC_CP16(gsrc, ldst)                                                 \
  __builtin_amdgcn_global_load_lds(                                            \
      (const __attribute__((address_space(1))) void*)(gsrc),                   \
      (__attribute__((address_space(3))) void*)(ldst), 16, 0, 0)

// ---------------------------------------------------------------------------
// Prep: transpose four 1024x1024 f32 weights -> (N,K) bf16, one kernel.
// dst chunks are contiguous: Wqkv_t (3 MB-chunks) then Wo_t.
// ---------------------------------------------------------------------------
__global__ void k_transpose4(const float* __restrict__ Wq,
                             const float* __restrict__ Wk,
                             const float* __restrict__ Wv,
                             const float* __restrict__ Wo,
                             short* __restrict__ dstBase) {
  __shared__ float tile[32][33];
  const int z = blockIdx.z;
  const float* src = (z == 0) ? Wq : (z == 1) ? Wk : (z == 2) ? Wv : Wo;
  short* dst = dstBase + (size_t)z * 1024 * 1024;
  const int bx = blockIdx.x * 32, by = blockIdx.y * 32;
  const int tx = threadIdx.x, ty = threadIdx.y;
#pragma unroll
  for (int i = 0; i < 32; i += 8)
    tile[ty + i][tx] = src[(size_t)(by + ty + i) * 1024 + bx + tx];
  __syncthreads();
#pragma unroll
  for (int i = 0; i < 32; i += 8)
    dst[(size_t)(bx + ty + i) * 1024 + by + tx] = f2bf(tile[tx][ty + i]);
}

// embW (119,1024) f32 -> embW_t (1024,128) bf16, zero-padded K 119->128
__global__ void k_embWt(const float* __restrict__ embW, short* __restrict__ dst) {
  const int idx = blockIdx.x * 256 + threadIdx.x;  // 1024*128
  const int n = idx >> 7, c = idx & 127;
  dst[idx] = f2bf((c < 119) ? embW[(size_t)c * 1024 + n] : 0.f);
}

// ---------------------------------------------------------------------------
// Embed: x[b,s,n] = sum_c board[b,c,s]*embW[c,n] + emb_b[n] + pos[s,n] (bf16)
// ---------------------------------------------------------------------------
__global__ __launch_bounds__(256) void k_embed(
    const float* __restrict__ board, const short* __restrict__ embWt,
    const float* __restrict__ emb_b, const float* __restrict__ pos,
    short* __restrict__ x) {
  __shared__ short As[64 * 136];   // [s][c], +8 pad breaks write conflicts
  __shared__ short Bs[128 * 32];   // [n][k-chunk]
  const int t = threadIdx.x, l = t & 63, w = t >> 6;
  const int quad = l >> 4, lan = l & 15;
  const int xcd = blockIdx.x & 7;
  const int lin = (blockIdx.x >> 3) + xcd * 1024;  // 8192/8
  const int b = lin >> 3, nBase = (lin & 7) << 7;
  const float* bb = board + (size_t)b * (119 * 64);
  const int s = t & 63;
#pragma unroll
  for (int it = 0; it < 16; ++it) {
    const int c0 = ((t >> 6) + it * 4) * 2;
    float u0 = (c0 < 119) ? bb[c0 * 64 + s] : 0.f;
    float u1 = (c0 + 1 < 119) ? bb[(c0 + 1) * 64 + s] : 0.f;
    short2 pr; pr.x = f2bf(u0); pr.y = f2bf(u1);
    *(short2*)&As[s * 136 + c0] = pr;
  }
  const short* Bg0 = embWt + (size_t)(nBase + (t >> 2)) * 128 + (t & 3) * 8;
  const short* Bg1 = Bg0 + (size_t)64 * 128;
  short* Bs0 = &Bs[(w * 16) * 32];
  short* Bs1 = &Bs[(64 + w * 16) * 32];
  floatx4 acc[4][2] = {};
  __syncthreads();
  for (int kk = 0; kk < 4; ++kk) {
    ASYNC_CP16(Bg0 + kk * 32, Bs0);
    ASYNC_CP16(Bg1 + kk * 32, Bs1);
    __syncthreads();
    bf16x8 af[4], bfr[2];
#pragma unroll
    for (int mt = 0; mt < 4; ++mt)
      af[mt] = *(const bf16x8*)&As[(mt * 16 + lan) * 136 + kk * 32 + quad * 8];
#pragma unroll
    for (int n2 = 0; n2 < 2; ++n2)
      bfr[n2] = *(const bf16x8*)&Bs[(w * 32 + n2 * 16 + lan) * 32 + quad * 8];
#pragma unroll
    for (int mt = 0; mt < 4; ++mt)
#pragma unroll
      for (int n2 = 0; n2 < 2; ++n2)
        acc[mt][n2] = mfma16(af[mt], bfr[n2], acc[mt][n2]);
    __syncthreads();
  }
#pragma unroll
  for (int n2 = 0; n2 < 2; ++n2) {
    const int n = nBase + w * 32 + n2 * 16 + lan;
    const float bi = emb_b[n];
#pragma unroll
    for (int mt = 0; mt < 4; ++mt) {
      const int s0 = mt * 16 + quad * 4;
      floatx4 v = acc[mt][n2];
#pragma unroll
      for (int r = 0; r < 4; ++r) {
        const int ss = s0 + r;
        x[((size_t)b * 64 + ss) * 1024 + n] = f2bf(v[r] + bi + pos[ss * 1024 + n]);
      }
    }
  }
}

// ---------------------------------------------------------------------------
// R1-proven 8-phase 256x256 BK=64 GEMM core. 512 threads = 8 waves (2Mx4N),
// per-wave output 128x64 = acc[8][4]. K=1024 -> NT=16 K-tiles.
// LDS (shorts): A: buf*16384 + kh*8192 + row*32 + slot*8 (2 bufs, 2 K-halves)
//               B: 32768 + same                           total 128 KiB
// Swizzle (involution, stage-source AND read): 16B-slot ^= (row>>1)&3
//   -> 8 consecutive rows cover all 8 bank quartets => 2-way (free).
// Stage queue per tile t: ph1 A-kh1(t+1)->buf^1, ph2 B-kh1(t+1)->buf^1,
//   ph3 A-kh0(t+2)->buf, ph4 B-kh0(t+2)->buf, then vmcnt(4) AFTER the MFMA
//   cluster (overlaps HBM drain with 16 MFMAs; still before the END barrier
//   so the ledger is unchanged): oldest 8 of 12 in-flight complete = tile
//   t+1 fully resident; kh0(t+2) stays in flight. Never drained to 0.
// ---------------------------------------------------------------------------
__device__ __forceinline__ void gemm8_core(
    const short* __restrict__ A, const short* __restrict__ Bt,
    short* lds, const int mBase, const int nBase, floatx4 (&acc)[8][4]) {
  const int t = threadIdx.x;            // 0..511
  const int w = t >> 6, l = t & 63;
  const int lan = l & 15, quad = l >> 4;
  const int wm = w >> 2, wn = w & 3;
  const int row0 = t >> 2;              // 0..127 (2nd load adds 128)
  const int sg = (t & 3) ^ ((t >> 3) & 3);
  const short* Ag = A + (size_t)(mBase + row0) * 1024 + sg * 8;
  const short* Bg = Bt + (size_t)(nBase + row0) * 1024 + sg * 8;
  const int swz = (quad ^ ((lan >> 1) & 3)) * 8;
  const int aRd = (wm * 128 + lan) * 32 + swz;
  const int bRd = 32768 + (wn * 64 + lan) * 32 + swz;
  const int wst = w * 512;              // wave's linear stage base (shorts)

#define STAGE_A8(ktgt, kh, buf) do {                                          \
    const short* _s = Ag + (ktgt) * 64 + (kh) * 32;                           \
    ASYNC_CP16(_s,          &lds[(buf) * 16384 + (kh) * 8192 + wst]);          \
    ASYNC_CP16(_s + 131072, &lds[(buf) * 16384 + (kh) * 8192 + 4096 + wst]);   \
  } while (0)
#define STAGE_B8(ktgt, kh, buf) do {                                          \
    const short* _s = Bg + (ktgt) * 64 + (kh) * 32;                           \
    ASYNC_CP16(_s,          &lds[32768 + (buf) * 16384 + (kh) * 8192 + wst]);  \
    ASYNC_CP16(_s + 131072,                                                    \
               &lds[32768 + (buf) * 16384 + (kh) * 8192 + 4096 + wst]);        \
  } while (0)
#define LDA8(dst, buf, ks, mh)                                                \
    _Pragma("unroll") for (int mf = 0; mf < 4; ++mf)                          \
      dst[mf] = *(const bf16x8*)&lds[(buf) * 16384 + (ks) * 8192 + aRd +      \
                                     ((mh) * 64 + mf * 16) * 32];
#define LDB8(dst, buf, ks)                                                    \
    _Pragma("unroll") for (int nf = 0; nf < 4; ++nf)                          \
      dst[nf] = *(const bf16x8*)&lds[(buf) * 16384 + (ks) * 8192 + bRd +      \
                                     nf * 512];
#define MMA8(mh, bfr)                                                         \
    _Pragma("unroll") for (int mf = 0; mf < 4; ++mf)                          \
      _Pragma("unroll") for (int nf = 0; nf < 4; ++nf)                        \
        acc[(mh) * 4 + mf][nf] = mfma16(af[mf], bfr[nf], acc[(mh) * 4 + mf][nf]);
#define PHASE_MID                                                             \
    __builtin_amdgcn_sched_barrier(0);                                        \
    __builtin_amdgcn_s_barrier();                                             \
    asm volatile("s_waitcnt lgkmcnt(0)" ::: "memory");                        \
    __builtin_amdgcn_sched_barrier(0);                                        \
    __builtin_amdgcn_s_setprio(1)
#define PHASE_END                                                             \
    __builtin_amdgcn_s_setprio(0);                                            \
    __builtin_amdgcn_sched_barrier(0);                                        \
    __builtin_amdgcn_s_barrier()
#define PHASE_END_VM                                                          \
    __builtin_amdgcn_s_setprio(0);                                            \
    __builtin_amdgcn_sched_barrier(0);                                        \
    asm volatile("s_waitcnt vmcnt(4)" ::: "memory");                          \
    __builtin_amdgcn_s_barrier()

  // prologue: tile0 (4 halves) + kh0 of tile1; vmcnt(4) => tile0 resident,
  // kh0(1) (newest 4 loads) may still be in flight.
  STAGE_A8(0, 0, 0); STAGE_B8(0, 0, 0);
  STAGE_A8(0, 1, 0); STAGE_B8(0, 1, 0);
  STAGE_A8(1, 0, 1); STAGE_B8(1, 0, 1);
  asm volatile("s_waitcnt vmcnt(4)" ::: "memory");
  __builtin_amdgcn_sched_barrier(0);
  __builtin_amdgcn_s_barrier();

#define TILE8(kt, cur) do {                                                   \
    const int k1 = ((kt) + 1 < 16) ? (kt) + 1 : 15;                           \
    const int k2 = ((kt) + 2 < 16) ? (kt) + 2 : 15;                           \
    bf16x8 af[4], bf0[4], bf1[4];                                             \
    /* ph1: ks=0 mh=0 */                                                      \
    LDA8(af, cur, 0, 0); LDB8(bf0, cur, 0);                                   \
    STAGE_A8(k1, 1, (cur) ^ 1);                                               \
    PHASE_MID; MMA8(0, bf0); PHASE_END;                                       \
    /* ph2: ks=0 mh=1 */                                                      \
    LDA8(af, cur, 0, 1);                                                      \
    STAGE_B8(k1, 1, (cur) ^ 1);                                               \
    PHASE_MID; MMA8(1, bf0); PHASE_END;                                       \
    /* ph3: ks=1 mh=0 */                                                      \
    LDA8(af, cur, 1, 0); LDB8(bf1, cur, 1);                                   \
    STAGE_A8(k2, 0, cur);                                                     \
    PHASE_MID; MMA8(0, bf1); PHASE_END;                                       \
    /* ph4: ks=1 mh=1 — vmcnt AFTER the MFMA cluster */                       \
    LDA8(af, cur, 1, 1);                                                      \
    STAGE_B8(k2, 0, cur);                                                     \
    PHASE_MID; MMA8(1, bf1); PHASE_END_VM;                                    \
  } while (0)

#pragma unroll 1
  for (int it = 0; it < 8; ++it) {
    TILE8(it * 2, 0);
    TILE8(it * 2 + 1, 1);
  }
  asm volatile("s_waitcnt vmcnt(0)" ::: "memory");
#undef TILE8
#undef PHASE_END_VM
#undef PHASE_END
#undef PHASE_MID
#undef MMA8
#undef LDB8
#undef LDA8
#undef STAGE_B8
#undef STAGE_A8
}

// ---------------------------------------------------------------------------
// QKV GEMM: x(65536,1024)bf16 @ Wqkv_t(3072,1024)bf16 -> q,k (b,h,s,dh) and
// v transposed (b,h,dh,s). 256^2 tiles: grid 256 mtiles x 12 ntiles = 3072.
// ---------------------------------------------------------------------------
__global__ __launch_bounds__(512, 2) void k_gemm_qkv8(
    const short* __restrict__ A, const short* __restrict__ Bt,
    const float* __restrict__ bq, const float* __restrict__ bk,
    const float* __restrict__ bv, short* __restrict__ qb,
    short* __restrict__ kb, short* __restrict__ vtb) {
  __shared__ short lds[65536];  // 128 KiB
  const int xcd = blockIdx.x & 7;
  const int lin = (blockIdx.x >> 3) + xcd * 384;   // 3072/8
  const int grp = lin / 96;                        // 8 mtiles * 12 ntiles
  const int rem = lin - grp * 96;
  const int mBase = ((grp << 3) + (rem & 7)) << 8;
  const int nBase = (rem >> 3) << 8;

  floatx4 acc[8][4] = {};
  gemm8_core(A, Bt, lds, mBase, nBase, acc);

  const int t = threadIdx.x, w = t >> 6, l = t & 63;
  const int lan = l & 15, quad = l >> 4;
  const int wm = w >> 2, wn = w & 3;
  // block's 256 cols lie entirely in one of q/k/v (1024 % 256 == 0)
  const int region = nBase >> 10;
  const int nb = nBase & 1023;
  const float* bias = (region == 0) ? bq : (region == 1) ? bk : bv;
  short* qk = (region == 0) ? qb : kb;
#pragma unroll
  for (int am = 0; am < 8; ++am) {
    const int m0 = mBase + wm * 128 + am * 16 + quad * 4;
    const int b = m0 >> 6, s0 = m0 & 63;
#pragma unroll
    for (int nf = 0; nf < 4; ++nf) {
      const int nn = nb + wn * 64 + nf * 16 + lan;
      const int h = nn >> 6, dh = nn & 63;
      const float bi = bias[nn];
      floatx4 v = acc[am][nf];
      if (region < 2) {
        short* dst = qk + (((size_t)b * 16 + h) * 64 + s0) * 64 + dh;
        dst[0]   = f2bf(v.x + bi);
        dst[64]  = f2bf(v.y + bi);
        dst[128] = f2bf(v.z + bi);
        dst[192] = f2bf(v.w + bi);
      } else {  // v stored transposed: vt[b,h,dh,s] -> contiguous in s
        bf16x4 pk = {f2bf(v.x + bi), f2bf(v.y + bi), f2bf(v.z + bi), f2bf(v.w + bi)};
        *(bf16x4*)(vtb + (((size_t)b * 16 + h) * 64 + dh) * 64 + s0) = pk;
      }
    }
  }
}

// ---------------------------------------------------------------------------
// O-proj GEMM + residual: y = o @ Wo + bo + x (bf16 out). 256 mtiles x 4 nt.
// ---------------------------------------------------------------------------
__global__ __launch_bounds__(512, 2) void k_gemm_oproj8(
    const short* __restrict__ A, const short* __restrict__ Bt,
    const float* __restrict__ bo, const short* __restrict__ xres,
    short* __restrict__ y) {
  __shared__ short lds[65536];
  const int xcd = blockIdx.x & 7;
  const int lin = (blockIdx.x >> 3) + xcd * 128;   // 1024/8
  const int grp = lin >> 5;                        // 8 mtiles * 4 ntiles
  const int rem = lin & 31;
  const int mBase = ((grp << 3) + (rem & 7)) << 8;
  const int nBase = (rem >> 3) << 8;

  floatx4 acc[8][4] = {};
  gemm8_core(A, Bt, lds, mBase, nBase, acc);

  const int t = threadIdx.x, w = t >> 6, l = t & 63;
  const int lan = l & 15, quad = l >> 4;
  const int wm = w >> 2, wn = w & 3;
#pragma unroll
  for (int nf = 0; nf < 4; ++nf) {
    const int n = nBase + wn * 64 + nf * 16 + lan;
    const float bi = bo[n];
#pragma unroll
    for (int am = 0; am < 8; ++am) {
      const int m0 = mBase + wm * 128 + am * 16 + quad * 4;
      floatx4 v = acc[am][nf];
#pragma unroll
      for (int r = 0; r < 4; ++r) {
        const size_t idx = (size_t)(m0 + r) * 1024 + n;
        y[idx] = f2bf(v[r] + bi + bf2f(xres[idx]));
      }
    }
  }
}

// ---------------------------------------------------------------------------
// Attention: one wave per (b,h). S = K @ Q^T so M=k-idx, N=q-idx: softmax
// over k is in-lane (16 regs) + shfl_xor(16,32). P -> LDS (bf16, padded
// rows) -> B-operand frags; o^T = V^T @ P via MFMA; /sum folded at store.
// ---------------------------------------------------------------------------
__global__ __launch_bounds__(256) void k_attn(
    const short* __restrict__ qb, const short* __restrict__ kb,
    const short* __restrict__ vtb, const float* __restrict__ rel_bias,
    short* __restrict__ ob) {
  __shared__ short P[4][64 * 72];  // per-wave, row stride 72
  const int t = threadIdx.x, l = t & 63, w = t >> 6;
  const int quad = l >> 4, lan = l & 15;
  const int b = blockIdx.x >> 2;
  const int h = (blockIdx.x & 3) * 4 + w;
  const short* q  = qb  + ((size_t)b * 16 + h) * 4096;
  const short* kp = kb  + ((size_t)b * 16 + h) * 4096;
  const short* vt = vtb + ((size_t)b * 16 + h) * 4096;
  const float* bias = rel_bias + (size_t)h * 4096;
  short* Pw = &P[w][0];

  bf16x8 kf[4][2], qf[4][2];
#pragma unroll
  for (int mt = 0; mt < 4; ++mt) {
    kf[mt][0] = *(const bf16x8*)&kp[(mt * 16 + lan) * 64 + quad * 8];
    kf[mt][1] = *(const bf16x8*)&kp[(mt * 16 + lan) * 64 + 32 + quad * 8];
  }
#pragma unroll
  for (int nt = 0; nt < 4; ++nt) {
    qf[nt][0] = *(const bf16x8*)&q[(nt * 16 + lan) * 64 + quad * 8];
    qf[nt][1] = *(const bf16x8*)&q[(nt * 16 + lan) * 64 + 32 + quad * 8];
  }
  floatx4 S[4][4];
#pragma unroll
  for (int mt = 0; mt < 4; ++mt)
#pragma unroll
    for (int nt = 0; nt < 4; ++nt) {
      floatx4 z = {0.f, 0.f, 0.f, 0.f};
      z = mfma16(kf[mt][0], qf[nt][0], z);
      S[mt][nt] = mfma16(kf[mt][1], qf[nt][1], z);
    }
  float rs[4];
#pragma unroll
  for (int nt = 0; nt < 4; ++nt) {
    const int qi = nt * 16 + lan;
    float sv[4][4];
    float m = -1e30f;
#pragma unroll
    for (int mt = 0; mt < 4; ++mt) {
      floatx4 bi = *(const floatx4*)&bias[qi * 64 + mt * 16 + quad * 4];
#pragma unroll
      for (int r = 0; r < 4; ++r) {
        sv[mt][r] = fmaf(S[mt][nt][r], 0.125f, bi[r]);
        m = fmaxf(m, sv[mt][r]);
      }
    }
    m = fmaxf(m, __shfl_xor(m, 16));
    m = fmaxf(m, __shfl_xor(m, 32));
    float sum = 0.f;
#pragma unroll
    for (int mt = 0; mt < 4; ++mt) {
      float p0 = exp2f((sv[mt][0] - m) * 1.4426950408889634f);
      float p1 = exp2f((sv[mt][1] - m) * 1.4426950408889634f);
      float p2 = exp2f((sv[mt][2] - m) * 1.4426950408889634f);
      float p3 = exp2f((sv[mt][3] - m) * 1.4426950408889634f);
      sum += p0 + p1 + p2 + p3;
      bf16x4 pk = {f2bf(p0), f2bf(p1), f2bf(p2), f2bf(p3)};
      *(bf16x4*)&Pw[qi * 72 + mt * 16 + quad * 4] = pk;
    }
    sum += __shfl_xor(sum, 16);
    sum += __shfl_xor(sum, 32);
    rs[nt] = 1.0f / sum;
  }
  bf16x8 pf[4][2];
#pragma unroll
  for (int nt = 0; nt < 4; ++nt) {
    pf[nt][0] = *(const bf16x8*)&Pw[(nt * 16 + lan) * 72 + quad * 8];
    pf[nt][1] = *(const bf16x8*)&Pw[(nt * 16 + lan) * 72 + 32 + quad * 8];
  }
#pragma unroll
  for (int mo = 0; mo < 4; ++mo) {
    bf16x8 vf0 = *(const bf16x8*)&vt[(mo * 16 + lan) * 64 + quad * 8];
    bf16x8 vf1 = *(const bf16x8*)&vt[(mo * 16 + lan) * 64 + 32 + quad * 8];
#pragma unroll
    for (int nt = 0; nt < 4; ++nt) {
      floatx4 z = {0.f, 0.f, 0.f, 0.f};
      z = mfma16(vf0, pf[nt][0], z);
      z = mfma16(vf1, pf[nt][1], z);
      const int qi = nt * 16 + lan;
      const int dh0 = mo * 16 + quad * 4;
      const float r = rs[nt];
      bf16x4 pk = {f2bf(z.x * r), f2bf(z.y * r), f2bf(z.z * r), f2bf(z.w * r)};
      *(bf16x4*)&ob[((size_t)b * 64 + qi) * 1024 + h * 64 + dh0] = pk;
    }
  }
}

// ---------------------------------------------------------------------------
// LayerNorm: one WAVE per row (D=1024), 4096 blocks x 4 waves x 4 iters.
// Lane holds 16 elems (2x bf16x8 = 32 B coalesced), shfl-only reduction,
// no LDS / no __syncthreads. Replaces the 65536-tiny-block version.
// ---------------------------------------------------------------------------
__global__ __launch_bounds__(256) void k_ln2(
    const short* __restrict__ y, const float* __restrict__ g,
    const float* __restrict__ be, float* __restrict__ out) {
  const int t = threadIdx.x, w = t >> 6, lane = t & 63;
#pragma unroll
  for (int it = 0; it < 4; ++it) {
    const int row = blockIdx.x * 16 + it * 4 + w;
    const short* yr = y + (size_t)row * 1024 + lane * 16;
    bf16x8 a = *(const bf16x8*)yr;
    bf16x8 c = *(const bf16x8*)(yr + 8);
    float v[16];
#pragma unroll
    for (int j = 0; j < 8; ++j) { v[j] = bf2f(a[j]); v[8 + j] = bf2f(c[j]); }
    float s = 0.f, s2 = 0.f;
#pragma unroll
    for (int j = 0; j < 16; ++j) { s += v[j]; s2 += v[j] * v[j]; }
#pragma unroll
    for (int off = 1; off < 64; off <<= 1) {
      s  += __shfl_xor(s, off);
      s2 += __shfl_xor(s2, off);
    }
    const float mu = s * (1.f / 1024.f);
    const float var = s2 * (1.f / 1024.f) - mu * mu;
    const float rstd = rsqrtf(var + 1e-5f);
    const int c0 = lane * 16;
    float* op = out + (size_t)row * 1024 + c0;
#pragma unroll
    for (int j4 = 0; j4 < 4; ++j4) {
      float4 gg = *(const float4*)&g[c0 + j4 * 4];
      float4 bb = *(const float4*)&be[c0 + j4 * 4];
      float4 o;
      o.x = (v[j4 * 4 + 0] - mu) * rstd * gg.x + bb.x;
      o.y = (v[j4 * 4 + 1] - mu) * rstd * gg.y + bb.y;
      o.z = (v[j4 * 4 + 2] - mu) * rstd * gg.z + bb.z;
      o.w = (v[j4 * 4 + 3] - mu) * rstd * gg.w + bb.w;
      *(float4*)&op[j4 * 4] = o;
    }
  }
}

// ---------------------------------------------------------------------------
extern "C" void kernel_launch(void* const* d_in, const int* in_sizes, int n_in,
                              void* d_out, int out_size, void* d_ws,
                              size_t ws_size, hipStream_t stream) {
  const float* board    = (const float*)d_in[0];
  const float* emb_W    = (const float*)d_in[1];
  const float* emb_b    = (const float*)d_in[2];
  const float* pos      = (const float*)d_in[3];
  const float* Wq       = (const float*)d_in[4];
  const float* bq       = (const float*)d_in[5];
  const float* Wk       = (const float*)d_in[6];
  const float* bk       = (const float*)d_in[7];
  const float* Wv       = (const float*)d_in[8];
  const float* bv       = (const float*)d_in[9];
  const float* Wo       = (const float*)d_in[10];
  const float* bo       = (const float*)d_in[11];
  const float* rel_bias = (const float*)d_in[12];
  const float* ln_g     = (const float*)d_in[13];
  const float* ln_b     = (const float*)d_in[14];

  // workspace carve (bf16 buffers). Peak ~648 MB.
  char* ws = (char*)d_ws;
  short* Wqkv_t = (short*)ws; ws += (size_t)3072 * 1024 * 2;   //  6 MB (N,K)
  short* Wo_t   = (short*)ws; ws += (size_t)1024 * 1024 * 2;   //  2 MB (N,K) — contiguous after Wqkv_t
  short* embWt  = (short*)ws; ws += (size_t)1024 * 128 * 2;    // .25 MB (N,Kpad)
  short* xb     = (short*)ws; ws += (size_t)65536 * 1024 * 2;  // 128 MB x bf16
  short* qb     = (short*)ws; ws += (size_t)16384 * 4096 * 2;  // 128 MB (b,h,s,dh)
  short* kb     = (short*)ws; ws += (size_t)16384 * 4096 * 2;  // 128 MB (b,h,s,dh)
  short* vtb    = (short*)ws; ws += (size_t)16384 * 4096 * 2;  // 128 MB (b,h,dh,s)
  short* ob     = (short*)ws; ws += (size_t)65536 * 1024 * 2;  // 128 MB (m,1024)
  short* yb     = kb;  // reuse: k no longer needed after attention

  k_transpose4<<<dim3(32, 32, 4), dim3(32, 8), 0, stream>>>(Wq, Wk, Wv, Wo,
                                                            Wqkv_t);
  k_embWt<<<512, 256, 0, stream>>>(emb_W, embWt);

  k_embed<<<8192, 256, 0, stream>>>(board, embWt, emb_b, pos, xb);
  k_gemm_qkv8<<<3072, 512, 0, stream>>>(xb, Wqkv_t, bq, bk, bv, qb, kb, vtb);
  k_attn<<<4096, 256, 0, stream>>>(qb, kb, vtb, rel_bias, ob);
  k_gemm_oproj8<<<1024, 512, 0, stream>>>(ob, Wo_t, bo, xb, yb);
  k_ln2<<<4096, 256, 0, stream>>>(yb, ln_g, ln_b, (float*)d_out);
}

// Round 6
// 1246.492 us; speedup vs baseline: 1.0880x; 1.0880x over previous
//
#include <hip/hip_runtime.h>
#include <hip/hip_bf16.h>
#include <stdint.h>

// ---------------------------------------------------------------------------
// BoardEmbeddingWithTopology: embed GEMM -> QKV GEMM -> per-head attention
// with learned 64x64 relative bias -> O-proj GEMM + residual -> LayerNorm.
// R7: qkv stays 256x256 8-phase (437us, 0 conflicts). oproj reverts to the
// 128x128 2-blocks/CU core (R1-vs-R5 rest-algebra: 256^2 oproj at 1024
// blocks = 1 block/CU x 4 serial rounds costs +156us) with the swizzle BUG
// FIXED (R5 used slot^=row&3 -> 4-way read conflicts; correct is
// slot^=(row>>1)&3, the function measured conflict-free in qkv8).
// ln2 (1 wave/row) + merged transpose kept from R6 (neutral, fewer launches).
// ---------------------------------------------------------------------------

typedef float  floatx4 __attribute__((ext_vector_type(4)));
typedef short  bf16x8  __attribute__((ext_vector_type(8)));
typedef short  bf16x4  __attribute__((ext_vector_type(4)));

__device__ __forceinline__ short f2bf(float f) {
  __hip_bfloat16 h = __float2bfloat16(f);
  return *reinterpret_cast<short*>(&h);
}
__device__ __forceinline__ float bf2f(short s) {
  union { float f; uint32_t u; } c;
  c.u = ((uint32_t)(uint16_t)s) << 16;
  return c.f;
}
__device__ __forceinline__ floatx4 mfma16(bf16x8 a, bf16x8 b, floatx4 c) {
  return __builtin_amdgcn_mfma_f32_16x16x32_bf16(a, b, c, 0, 0, 0);
}

// async global->LDS, 16B per lane; lds dst must be wave-uniform base.
#define ASYNC_CP16(gsrc, ldst)                                                 \
  __builtin_amdgcn_global_load_lds(                                            \
      (const __attribute__((address_space(1))) void*)(gsrc),                   \
      (__attribute__((address_space(3))) void*)(ldst), 16, 0, 0)

// ---------------------------------------------------------------------------
// Prep: transpose four 1024x1024 f32 weights -> (N,K) bf16, one kernel.
// dst chunks contiguous: Wqkv_t (3 chunks) then Wo_t.
// ---------------------------------------------------------------------------
__global__ void k_transpose4(const float* __restrict__ Wq,
                             const float* __restrict__ Wk,
                             const float* __restrict__ Wv,
                             const float* __restrict__ Wo,
                             short* __restrict__ dstBase) {
  __shared__ float tile[32][33];
  const int z = blockIdx.z;
  const float* src = (z == 0) ? Wq : (z == 1) ? Wk : (z == 2) ? Wv : Wo;
  short* dst = dstBase + (size_t)z * 1024 * 1024;
  const int bx = blockIdx.x * 32, by = blockIdx.y * 32;
  const int tx = threadIdx.x, ty = threadIdx.y;
#pragma unroll
  for (int i = 0; i < 32; i += 8)
    tile[ty + i][tx] = src[(size_t)(by + ty + i) * 1024 + bx + tx];
  __syncthreads();
#pragma unroll
  for (int i = 0; i < 32; i += 8)
    dst[(size_t)(bx + ty + i) * 1024 + by + tx] = f2bf(tile[tx][ty + i]);
}

// embW (119,1024) f32 -> embW_t (1024,128) bf16, zero-padded K 119->128
__global__ void k_embWt(const float* __restrict__ embW, short* __restrict__ dst) {
  const int idx = blockIdx.x * 256 + threadIdx.x;  // 1024*128
  const int n = idx >> 7, c = idx & 127;
  dst[idx] = f2bf((c < 119) ? embW[(size_t)c * 1024 + n] : 0.f);
}

// ---------------------------------------------------------------------------
// Embed: x[b,s,n] = sum_c board[b,c,s]*embW[c,n] + emb_b[n] + pos[s,n] (bf16)
// ---------------------------------------------------------------------------
__global__ __launch_bounds__(256) void k_embed(
    const float* __restrict__ board, const short* __restrict__ embWt,
    const float* __restrict__ emb_b, const float* __restrict__ pos,
    short* __restrict__ x) {
  __shared__ short As[64 * 136];   // [s][c], +8 pad breaks write conflicts
  __shared__ short Bs[128 * 32];   // [n][k-chunk]
  const int t = threadIdx.x, l = t & 63, w = t >> 6;
  const int quad = l >> 4, lan = l & 15;
  const int xcd = blockIdx.x & 7;
  const int lin = (blockIdx.x >> 3) + xcd * 1024;  // 8192/8
  const int b = lin >> 3, nBase = (lin & 7) << 7;
  const float* bb = board + (size_t)b * (119 * 64);
  const int s = t & 63;
#pragma unroll
  for (int it = 0; it < 16; ++it) {
    const int c0 = ((t >> 6) + it * 4) * 2;
    float u0 = (c0 < 119) ? bb[c0 * 64 + s] : 0.f;
    float u1 = (c0 + 1 < 119) ? bb[(c0 + 1) * 64 + s] : 0.f;
    short2 pr; pr.x = f2bf(u0); pr.y = f2bf(u1);
    *(short2*)&As[s * 136 + c0] = pr;
  }
  const short* Bg0 = embWt + (size_t)(nBase + (t >> 2)) * 128 + (t & 3) * 8;
  const short* Bg1 = Bg0 + (size_t)64 * 128;
  short* Bs0 = &Bs[(w * 16) * 32];
  short* Bs1 = &Bs[(64 + w * 16) * 32];
  floatx4 acc[4][2] = {};
  __syncthreads();
  for (int kk = 0; kk < 4; ++kk) {
    ASYNC_CP16(Bg0 + kk * 32, Bs0);
    ASYNC_CP16(Bg1 + kk * 32, Bs1);
    __syncthreads();
    bf16x8 af[4], bfr[2];
#pragma unroll
    for (int mt = 0; mt < 4; ++mt)
      af[mt] = *(const bf16x8*)&As[(mt * 16 + lan) * 136 + kk * 32 + quad * 8];
#pragma unroll
    for (int n2 = 0; n2 < 2; ++n2)
      bfr[n2] = *(const bf16x8*)&Bs[(w * 32 + n2 * 16 + lan) * 32 + quad * 8];
#pragma unroll
    for (int mt = 0; mt < 4; ++mt)
#pragma unroll
      for (int n2 = 0; n2 < 2; ++n2)
        acc[mt][n2] = mfma16(af[mt], bfr[n2], acc[mt][n2]);
    __syncthreads();
  }
#pragma unroll
  for (int n2 = 0; n2 < 2; ++n2) {
    const int n = nBase + w * 32 + n2 * 16 + lan;
    const float bi = emb_b[n];
#pragma unroll
    for (int mt = 0; mt < 4; ++mt) {
      const int s0 = mt * 16 + quad * 4;
      floatx4 v = acc[mt][n2];
#pragma unroll
      for (int r = 0; r < 4; ++r) {
        const int ss = s0 + r;
        x[((size_t)b * 64 + ss) * 1024 + n] = f2bf(v[r] + bi + pos[ss * 1024 + n]);
      }
    }
  }
}

// ---------------------------------------------------------------------------
// 8-phase 256x256 BK=64 GEMM core (R1-proven). 512 threads = 8 waves (2Mx4N),
// per-wave output 128x64 = acc[8][4]. K=1024 -> NT=16 K-tiles.
// Swizzle (involution, stage-source AND read): 16B-slot ^= (row>>1)&3.
// vmcnt(4) once per tile after ph4's MFMA cluster; never drained in loop.
// ---------------------------------------------------------------------------
__device__ __forceinline__ void gemm8_core(
    const short* __restrict__ A, const short* __restrict__ Bt,
    short* lds, const int mBase, const int nBase, floatx4 (&acc)[8][4]) {
  const int t = threadIdx.x;            // 0..511
  const int w = t >> 6, l = t & 63;
  const int lan = l & 15, quad = l >> 4;
  const int wm = w >> 2, wn = w & 3;
  const int row0 = t >> 2;              // 0..127 (2nd load adds 128)
  const int sg = (t & 3) ^ ((t >> 3) & 3);
  const short* Ag = A + (size_t)(mBase + row0) * 1024 + sg * 8;
  const short* Bg = Bt + (size_t)(nBase + row0) * 1024 + sg * 8;
  const int swz = (quad ^ ((lan >> 1) & 3)) * 8;
  const int aRd = (wm * 128 + lan) * 32 + swz;
  const int bRd = 32768 + (wn * 64 + lan) * 32 + swz;
  const int wst = w * 512;              // wave's linear stage base (shorts)

#define STAGE_A8(ktgt, kh, buf) do {                                          \
    const short* _s = Ag + (ktgt) * 64 + (kh) * 32;                           \
    ASYNC_CP16(_s,          &lds[(buf) * 16384 + (kh) * 8192 + wst]);          \
    ASYNC_CP16(_s + 131072, &lds[(buf) * 16384 + (kh) * 8192 + 4096 + wst]);   \
  } while (0)
#define STAGE_B8(ktgt, kh, buf) do {                                          \
    const short* _s = Bg + (ktgt) * 64 + (kh) * 32;                           \
    ASYNC_CP16(_s,          &lds[32768 + (buf) * 16384 + (kh) * 8192 + wst]);  \
    ASYNC_CP16(_s + 131072,                                                    \
               &lds[32768 + (buf) * 16384 + (kh) * 8192 + 4096 + wst]);        \
  } while (0)
#define LDA8(dst, buf, ks, mh)                                                \
    _Pragma("unroll") for (int mf = 0; mf < 4; ++mf)                          \
      dst[mf] = *(const bf16x8*)&lds[(buf) * 16384 + (ks) * 8192 + aRd +      \
                                     ((mh) * 64 + mf * 16) * 32];
#define LDB8(dst, buf, ks)                                                    \
    _Pragma("unroll") for (int nf = 0; nf < 4; ++nf)                          \
      dst[nf] = *(const bf16x8*)&lds[(buf) * 16384 + (ks) * 8192 + bRd +      \
                                     nf * 512];
#define MMA8(mh, bfr)                                                         \
    _Pragma("unroll") for (int mf = 0; mf < 4; ++mf)                          \
      _Pragma("unroll") for (int nf = 0; nf < 4; ++nf)                        \
        acc[(mh) * 4 + mf][nf] = mfma16(af[mf], bfr[nf], acc[(mh) * 4 + mf][nf]);
#define PHASE_MID                                                             \
    __builtin_amdgcn_sched_barrier(0);                                        \
    __builtin_amdgcn_s_barrier();                                             \
    asm volatile("s_waitcnt lgkmcnt(0)" ::: "memory");                        \
    __builtin_amdgcn_sched_barrier(0);                                        \
    __builtin_amdgcn_s_setprio(1)
#define PHASE_END                                                             \
    __builtin_amdgcn_s_setprio(0);                                            \
    __builtin_amdgcn_sched_barrier(0);                                        \
    __builtin_amdgcn_s_barrier()
#define PHASE_END_VM                                                          \
    __builtin_amdgcn_s_setprio(0);                                            \
    __builtin_amdgcn_sched_barrier(0);                                        \
    asm volatile("s_waitcnt vmcnt(4)" ::: "memory");                          \
    __builtin_amdgcn_s_barrier()

  // prologue: tile0 (4 halves) + kh0 of tile1; vmcnt(4) => tile0 resident.
  STAGE_A8(0, 0, 0); STAGE_B8(0, 0, 0);
  STAGE_A8(0, 1, 0); STAGE_B8(0, 1, 0);
  STAGE_A8(1, 0, 1); STAGE_B8(1, 0, 1);
  asm volatile("s_waitcnt vmcnt(4)" ::: "memory");
  __builtin_amdgcn_sched_barrier(0);
  __builtin_amdgcn_s_barrier();

#define TILE8(kt, cur) do {                                                   \
    const int k1 = ((kt) + 1 < 16) ? (kt) + 1 : 15;                           \
    const int k2 = ((kt) + 2 < 16) ? (kt) + 2 : 15;                           \
    bf16x8 af[4], bf0[4], bf1[4];                                             \
    LDA8(af, cur, 0, 0); LDB8(bf0, cur, 0);                                   \
    STAGE_A8(k1, 1, (cur) ^ 1);                                               \
    PHASE_MID; MMA8(0, bf0); PHASE_END;                                       \
    LDA8(af, cur, 0, 1);                                                      \
    STAGE_B8(k1, 1, (cur) ^ 1);                                               \
    PHASE_MID; MMA8(1, bf0); PHASE_END;                                       \
    LDA8(af, cur, 1, 0); LDB8(bf1, cur, 1);                                   \
    STAGE_A8(k2, 0, cur);                                                     \
    PHASE_MID; MMA8(0, bf1); PHASE_END;                                       \
    LDA8(af, cur, 1, 1);                                                      \
    STAGE_B8(k2, 0, cur);                                                     \
    PHASE_MID; MMA8(1, bf1); PHASE_END_VM;                                    \
  } while (0)

#pragma unroll 1
  for (int it = 0; it < 8; ++it) {
    TILE8(it * 2, 0);
    TILE8(it * 2 + 1, 1);
  }
  asm volatile("s_waitcnt vmcnt(0)" ::: "memory");
#undef TILE8
#undef PHASE_END_VM
#undef PHASE_END
#undef PHASE_MID
#undef MMA8
#undef LDB8
#undef LDA8
#undef STAGE_B8
#undef STAGE_A8
}

// ---------------------------------------------------------------------------
// 128x128 BK=64 GEMM core, 2 blocks/CU (64 KiB LDS). 8 waves (4M x 2N),
// wave tile 32x64 -> acc[2][4]. 2 phases/tile; vmcnt(4) per phase.
// FIXED swizzle: 16B-slot ^= (row>>1)&3 on stage source AND read
// (R5's row&3 variant caused 4-way read conflicts, 7.55e7/dispatch).
// ---------------------------------------------------------------------------
__device__ __forceinline__ void gemm128_core(
    const short* __restrict__ A, const short* __restrict__ Bt,
    short* lds, const int mBase, const int nBase, floatx4 (&acc)[2][4]) {
  const int t = threadIdx.x;            // 0..511
  const int w = t >> 6, l = t & 63;
  const int lan = l & 15, quad = l >> 4;
  const int wm = w >> 1, wn = w & 1;
  const int srow = t >> 2;              // 0..127
  const int sg = ((t & 3) ^ ((t >> 3) & 3)) * 8;        // slot ^= (row>>1)&3
  const short* Ag = A + (size_t)(mBase + srow) * 1024 + sg;
  const short* Bg = Bt + (size_t)(nBase + srow) * 1024 + sg;
  const int swz = (quad ^ ((lan >> 1) & 3)) * 8;        // same involution
  const int aRd = (wm * 32 + lan) * 32 + swz;
  const int bRd = 8192 + (wn * 64 + lan) * 32 + swz;
  const int wst = w * 512;

#define STAGE_AB(ko, kh, buf) do {                                            \
    ASYNC_CP16(Ag + (ko) + (kh) * 32,                                         \
               &lds[(buf) * 16384 + (kh) * 4096 + wst]);                       \
    ASYNC_CP16(Bg + (ko) + (kh) * 32,                                         \
               &lds[8192 + (buf) * 16384 + (kh) * 4096 + wst]);                \
  } while (0)

#define PHASE(buf, kh, stko, stkh, stbuf) do {                                \
    bf16x8 af[2], bfr[4];                                                     \
    _Pragma("unroll") for (int am = 0; am < 2; ++am)                          \
      af[am] = *(const bf16x8*)&lds[(buf) * 16384 + (kh) * 4096 + aRd +       \
                                    am * 512];                                 \
    _Pragma("unroll") for (int nf = 0; nf < 4; ++nf)                          \
      bfr[nf] = *(const bf16x8*)&lds[(buf) * 16384 + (kh) * 4096 + bRd +      \
                                     nf * 512];                                \
    STAGE_AB(stko, stkh, stbuf);                                              \
    __builtin_amdgcn_sched_barrier(0);                                        \
    __builtin_amdgcn_s_barrier();                                             \
    asm volatile("s_waitcnt lgkmcnt(0)" ::: "memory");                        \
    __builtin_amdgcn_sched_barrier(0);                                        \
    __builtin_amdgcn_s_setprio(1);                                            \
    _Pragma("unroll") for (int am = 0; am < 2; ++am)                          \
      _Pragma("unroll") for (int nf = 0; nf < 4; ++nf)                        \
        acc[am][nf] = mfma16(af[am], bfr[nf], acc[am][nf]);                   \
    __builtin_amdgcn_s_setprio(0);                                            \
    __builtin_amdgcn_sched_barrier(0);                                        \
    asm volatile("s_waitcnt vmcnt(4)" ::: "memory");                          \
    __builtin_amdgcn_s_barrier();                                             \
  } while (0)

  STAGE_AB(0, 0, 0);
  STAGE_AB(0, 1, 0);
  STAGE_AB(64, 0, 1);
  asm volatile("s_waitcnt vmcnt(4)" ::: "memory");
  __builtin_amdgcn_sched_barrier(0);
  __builtin_amdgcn_s_barrier();

#pragma unroll 1
  for (int tt = 0; tt < 16; tt += 2) {
    const int k1 = (tt + 1) * 64;
    const int k2 = (tt + 2 < 16 ? tt + 2 : 15) * 64;
    const int k3 = (tt + 3 < 16 ? tt + 3 : 15) * 64;
    PHASE(0, 0, k1, 1, 1);   // stage kh1(tt+1) -> buf1
    PHASE(0, 1, k2, 0, 0);   // stage kh0(tt+2) -> buf0
    PHASE(1, 0, k2, 1, 0);   // stage kh1(tt+2) -> buf0
    PHASE(1, 1, k3, 0, 1);   // stage kh0(tt+3) -> buf1
  }
  asm volatile("s_waitcnt vmcnt(0)" ::: "memory");
  __builtin_amdgcn_s_barrier();
#undef PHASE
#undef STAGE_AB
}

// ---------------------------------------------------------------------------
// QKV GEMM: x(65536,1024)bf16 @ Wqkv_t(3072,1024)bf16 -> q,k (b,h,s,dh) and
// v transposed (b,h,dh,s). 256^2 tiles: 256 mtiles x 12 ntiles = 3072 blocks.
// ---------------------------------------------------------------------------
__global__ __launch_bounds__(512, 2) void k_gemm_qkv8(
    const short* __restrict__ A, const short* __restrict__ Bt,
    const float* __restrict__ bq, const float* __restrict__ bk,
    const float* __restrict__ bv, short* __restrict__ qb,
    short* __restrict__ kb, short* __restrict__ vtb) {
  __shared__ short lds[65536];  // 128 KiB
  const int xcd = blockIdx.x & 7;
  const int lin = (blockIdx.x >> 3) + xcd * 384;   // 3072/8
  const int grp = lin / 96;                        // 8 mtiles * 12 ntiles
  const int rem = lin - grp * 96;
  const int mBase = ((grp << 3) + (rem & 7)) << 8;
  const int nBase = (rem >> 3) << 8;

  floatx4 acc[8][4] = {};
  gemm8_core(A, Bt, lds, mBase, nBase, acc);

  const int t = threadIdx.x, w = t >> 6, l = t & 63;
  const int lan = l & 15, quad = l >> 4;
  const int wm = w >> 2, wn = w & 3;
  // block's 256 cols lie entirely in one of q/k/v (1024 % 256 == 0)
  const int region = nBase >> 10;
  const int nb = nBase & 1023;
  const float* bias = (region == 0) ? bq : (region == 1) ? bk : bv;
  short* qk = (region == 0) ? qb : kb;
#pragma unroll
  for (int am = 0; am < 8; ++am) {
    const int m0 = mBase + wm * 128 + am * 16 + quad * 4;
    const int b = m0 >> 6, s0 = m0 & 63;
#pragma unroll
    for (int nf = 0; nf < 4; ++nf) {
      const int nn = nb + wn * 64 + nf * 16 + lan;
      const int h = nn >> 6, dh = nn & 63;
      const float bi = bias[nn];
      floatx4 v = acc[am][nf];
      if (region < 2) {
        short* dst = qk + (((size_t)b * 16 + h) * 64 + s0) * 64 + dh;
        dst[0]   = f2bf(v.x + bi);
        dst[64]  = f2bf(v.y + bi);
        dst[128] = f2bf(v.z + bi);
        dst[192] = f2bf(v.w + bi);
      } else {  // v stored transposed: vt[b,h,dh,s] -> contiguous in s
        bf16x4 pk = {f2bf(v.x + bi), f2bf(v.y + bi), f2bf(v.z + bi), f2bf(v.w + bi)};
        *(bf16x4*)(vtb + (((size_t)b * 16 + h) * 64 + dh) * 64 + s0) = pk;
      }
    }
  }
}

// ---------------------------------------------------------------------------
// O-proj GEMM + residual: y = o @ Wo + bo + x (bf16 out).
// 128^2 tiles: 512 mtiles x 8 ntiles = 4096 blocks, 2 blocks/CU.
// ---------------------------------------------------------------------------
__global__ __launch_bounds__(512, 4) void k_gemm_oproj10(
    const short* __restrict__ A, const short* __restrict__ Bt,
    const float* __restrict__ bo, const short* __restrict__ xres,
    short* __restrict__ y) {
  __shared__ short lds[32768];  // 64 KiB
  const int xcd = blockIdx.x & 7;
  const int lin = (blockIdx.x >> 3) + xcd * 512;    // 4096/8
  const int grp = lin >> 6;                         // 8 mtiles * 8 ntiles
  const int rem = lin & 63;
  const int mBase = ((grp << 3) + (rem & 7)) << 7;
  const int nBase = (rem >> 3) << 7;

  floatx4 acc[2][4] = {};
  gemm128_core(A, Bt, lds, mBase, nBase, acc);

  const int t = threadIdx.x, w = t >> 6, l = t & 63;
  const int lan = l & 15, quad = l >> 4;
  const int wm = w >> 1, wn = w & 1;
#pragma unroll
  for (int nf = 0; nf < 4; ++nf) {
    const int n = nBase + wn * 64 + nf * 16 + lan;
    const float bi = bo[n];
#pragma unroll
    for (int am = 0; am < 2; ++am) {
      const int m0 = mBase + wm * 32 + am * 16 + quad * 4;
      floatx4 v = acc[am][nf];
#pragma unroll
      for (int r = 0; r < 4; ++r) {
        const size_t idx = (size_t)(m0 + r) * 1024 + n;
        y[idx] = f2bf(v[r] + bi + bf2f(xres[idx]));
      }
    }
  }
}

// ---------------------------------------------------------------------------
// Attention: one wave per (b,h). S = K @ Q^T so M=k-idx, N=q-idx: softmax
// over k is in-lane (16 regs) + shfl_xor(16,32). P -> LDS (bf16, padded
// rows) -> B-operand frags; o^T = V^T @ P via MFMA; /sum folded at store.
// ---------------------------------------------------------------------------
__global__ __launch_bounds__(256) void k_attn(
    const short* __restrict__ qb, const short* __restrict__ kb,
    const short* __restrict__ vtb, const float* __restrict__ rel_bias,
    short* __restrict__ ob) {
  __shared__ short P[4][64 * 72];  // per-wave, row stride 72
  const int t = threadIdx.x, l = t & 63, w = t >> 6;
  const int quad = l >> 4, lan = l & 15;
  const int b = blockIdx.x >> 2;
  const int h = (blockIdx.x & 3) * 4 + w;
  const short* q  = qb  + ((size_t)b * 16 + h) * 4096;
  const short* kp = kb  + ((size_t)b * 16 + h) * 4096;
  const short* vt = vtb + ((size_t)b * 16 + h) * 4096;
  const float* bias = rel_bias + (size_t)h * 4096;
  short* Pw = &P[w][0];

  bf16x8 kf[4][2], qf[4][2];
#pragma unroll
  for (int mt = 0; mt < 4; ++mt) {
    kf[mt][0] = *(const bf16x8*)&kp[(mt * 16 + lan) * 64 + quad * 8];
    kf[mt][1] = *(const bf16x8*)&kp[(mt * 16 + lan) * 64 + 32 + quad * 8];
  }
#pragma unroll
  for (int nt = 0; nt < 4; ++nt) {
    qf[nt][0] = *(const bf16x8*)&q[(nt * 16 + lan) * 64 + quad * 8];
    qf[nt][1] = *(const bf16x8*)&q[(nt * 16 + lan) * 64 + 32 + quad * 8];
  }
  floatx4 S[4][4];
#pragma unroll
  for (int mt = 0; mt < 4; ++mt)
#pragma unroll
    for (int nt = 0; nt < 4; ++nt) {
      floatx4 z = {0.f, 0.f, 0.f, 0.f};
      z = mfma16(kf[mt][0], qf[nt][0], z);
      S[mt][nt] = mfma16(kf[mt][1], qf[nt][1], z);
    }
  float rs[4];
#pragma unroll
  for (int nt = 0; nt < 4; ++nt) {
    const int qi = nt * 16 + lan;
    float sv[4][4];
    float m = -1e30f;
#pragma unroll
    for (int mt = 0; mt < 4; ++mt) {
      floatx4 bi = *(const floatx4*)&bias[qi * 64 + mt * 16 + quad * 4];
#pragma unroll
      for (int r = 0; r < 4; ++r) {
        sv[mt][r] = fmaf(S[mt][nt][r], 0.125f, bi[r]);
        m = fmaxf(m, sv[mt][r]);
      }
    }
    m = fmaxf(m, __shfl_xor(m, 16));
    m = fmaxf(m, __shfl_xor(m, 32));
    float sum = 0.f;
#pragma unroll
    for (int mt = 0; mt < 4; ++mt) {
      float p0 = exp2f((sv[mt][0] - m) * 1.4426950408889634f);
      float p1 = exp2f((sv[mt][1] - m) * 1.4426950408889634f);
      float p2 = exp2f((sv[mt][2] - m) * 1.4426950408889634f);
      float p3 = exp2f((sv[mt][3] - m) * 1.4426950408889634f);
      sum += p0 + p1 + p2 + p3;
      bf16x4 pk = {f2bf(p0), f2bf(p1), f2bf(p2), f2bf(p3)};
      *(bf16x4*)&Pw[qi * 72 + mt * 16 + quad * 4] = pk;
    }
    sum += __shfl_xor(sum, 16);
    sum += __shfl_xor(sum, 32);
    rs[nt] = 1.0f / sum;
  }
  bf16x8 pf[4][2];
#pragma unroll
  for (int nt = 0; nt < 4; ++nt) {
    pf[nt][0] = *(const bf16x8*)&Pw[(nt * 16 + lan) * 72 + quad * 8];
    pf[nt][1] = *(const bf16x8*)&Pw[(nt * 16 + lan) * 72 + 32 + quad * 8];
  }
#pragma unroll
  for (int mo = 0; mo < 4; ++mo) {
    bf16x8 vf0 = *(const bf16x8*)&vt[(mo * 16 + lan) * 64 + quad * 8];
    bf16x8 vf1 = *(const bf16x8*)&vt[(mo * 16 + lan) * 64 + 32 + quad * 8];
#pragma unroll
    for (int nt = 0; nt < 4; ++nt) {
      floatx4 z = {0.f, 0.f, 0.f, 0.f};
      z = mfma16(vf0, pf[nt][0], z);
      z = mfma16(vf1, pf[nt][1], z);
      const int qi = nt * 16 + lan;
      const int dh0 = mo * 16 + quad * 4;
      const float r = rs[nt];
      bf16x4 pk = {f2bf(z.x * r), f2bf(z.y * r), f2bf(z.z * r), f2bf(z.w * r)};
      *(bf16x4*)&ob[((size_t)b * 64 + qi) * 1024 + h * 64 + dh0] = pk;
    }
  }
}

// ---------------------------------------------------------------------------
// LayerNorm: one WAVE per row (D=1024), 4096 blocks x 4 waves x 4 iters.
// ---------------------------------------------------------------------------
__global__ __launch_bounds__(256) void k_ln2(
    const short* __restrict__ y, const float* __restrict__ g,
    const float* __restrict__ be, float* __restrict__ out) {
  const int t = threadIdx.x, w = t >> 6, lane = t & 63;
#pragma unroll
  for (int it = 0; it < 4; ++it) {
    const int row = blockIdx.x * 16 + it * 4 + w;
    const short* yr = y + (size_t)row * 1024 + lane * 16;
    bf16x8 a = *(const bf16x8*)yr;
    bf16x8 c = *(const bf16x8*)(yr + 8);
    float v[16];
#pragma unroll
    for (int j = 0; j < 8; ++j) { v[j] = bf2f(a[j]); v[8 + j] = bf2f(c[j]); }
    float s = 0.f, s2 = 0.f;
#pragma unroll
    for (int j = 0; j < 16; ++j) { s += v[j]; s2 += v[j] * v[j]; }
#pragma unroll
    for (int off = 1; off < 64; off <<= 1) {
      s  += __shfl_xor(s, off);
      s2 += __shfl_xor(s2, off);
    }
    const float mu = s * (1.f / 1024.f);
    const float var = s2 * (1.f / 1024.f) - mu * mu;
    const float rstd = rsqrtf(var + 1e-5f);
    const int c0 = lane * 16;
    float* op = out + (size_t)row * 1024 + c0;
#pragma unroll
    for (int j4 = 0; j4 < 4; ++j4) {
      float4 gg = *(const float4*)&g[c0 + j4 * 4];
      float4 bb = *(const float4*)&be[c0 + j4 * 4];
      float4 o;
      o.x = (v[j4 * 4 + 0] - mu) * rstd * gg.x + bb.x;
      o.y = (v[j4 * 4 + 1] - mu) * rstd * gg.y + bb.y;
      o.z = (v[j4 * 4 + 2] - mu) * rstd * gg.z + bb.z;
      o.w = (v[j4 * 4 + 3] - mu) * rstd * gg.w + bb.w;
      *(float4*)&op[j4 * 4] = o;
    }
  }
}

// ---------------------------------------------------------------------------
extern "C" void kernel_launch(void* const* d_in, const int* in_sizes, int n_in,
                              void* d_out, int out_size, void* d_ws,
                              size_t ws_size, hipStream_t stream) {
  const float* board    = (const float*)d_in[0];
  const float* emb_W    = (const float*)d_in[1];
  const float* emb_b    = (const float*)d_in[2];
  const float* pos      = (const float*)d_in[3];
  const float* Wq       = (const float*)d_in[4];
  const float* bq       = (const float*)d_in[5];
  const float* Wk       = (const float*)d_in[6];
  const float* bk       = (const float*)d_in[7];
  const float* Wv       = (const float*)d_in[8];
  const float* bv       = (const float*)d_in[9];
  const float* Wo       = (const float*)d_in[10];
  const float* bo       = (const float*)d_in[11];
  const float* rel_bias = (const float*)d_in[12];
  const float* ln_g     = (const float*)d_in[13];
  const float* ln_b     = (const float*)d_in[14];

  // workspace carve (bf16 buffers). Peak ~648 MB.
  char* ws = (char*)d_ws;
  short* Wqkv_t = (short*)ws; ws += (size_t)3072 * 1024 * 2;   //  6 MB (N,K)
  short* Wo_t   = (short*)ws; ws += (size_t)1024 * 1024 * 2;   //  2 MB (N,K) — contiguous after Wqkv_t
  short* embWt  = (short*)ws; ws += (size_t)1024 * 128 * 2;    // .25 MB (N,Kpad)
  short* xb     = (short*)ws; ws += (size_t)65536 * 1024 * 2;  // 128 MB x bf16
  short* qb     = (short*)ws; ws += (size_t)16384 * 4096 * 2;  // 128 MB (b,h,s,dh)
  short* kb     = (short*)ws; ws += (size_t)16384 * 4096 * 2;  // 128 MB (b,h,s,dh)
  short* vtb    = (short*)ws; ws += (size_t)16384 * 4096 * 2;  // 128 MB (b,h,dh,s)
  short* ob     = (short*)ws; ws += (size_t)65536 * 1024 * 2;  // 128 MB (m,1024)
  short* yb     = kb;  // reuse: k no longer needed after attention

  k_transpose4<<<dim3(32, 32, 4), dim3(32, 8), 0, stream>>>(Wq, Wk, Wv, Wo,
                                                            Wqkv_t);
  k_embWt<<<512, 256, 0, stream>>>(emb_W, embWt);

  k_embed<<<8192, 256, 0, stream>>>(board, embWt, emb_b, pos, xb);
  k_gemm_qkv8<<<3072, 512, 0, stream>>>(xb, Wqkv_t, bq, bk, bv, qb, kb, vtb);
  k_attn<<<4096, 256, 0, stream>>>(qb, kb, vtb, rel_bias, ob);
  k_gemm_oproj10<<<4096, 512, 0, stream>>>(ob, Wo_t, bo, xb, yb);
  k_ln2<<<4096, 256, 0, stream>>>(yb, ln_g, ln_b, (float*)d_out);
}